// Round 8
// baseline (808.005 us; speedup 1.0000x reference)
//
#include <hip/hip_runtime.h>
#include <math.h>

#define T_LEN 1024
#define B_SZ  256
#define I_SZ  128
#define H_SZ  64
#define G_SZ  256   // 4*H
#define SUB   32    // recurrence steps per LDS-staged XG sub-chunk

typedef float f32x8 __attribute__((ext_vector_type(8)));

__device__ __forceinline__ float fast_sigmoid(float x) {
    float e = __expf(-x);
    return __builtin_amdgcn_rcpf(1.0f + e);
}
__device__ __forceinline__ float fast_tanh(float x) {   // safe for any |x|
    float e = __expf(-2.0f * fabsf(x));
    float r = (1.0f - e) * __builtin_amdgcn_rcpf(1.0f + e);
    return copysignf(r, x);
}

#define LD8PIN(V, P)                                                        \
    {   float4 t0_ = *reinterpret_cast<const float4*>(P);                   \
        float4 t1_ = *reinterpret_cast<const float4*>((P) + 4);             \
        V = (f32x8){t0_.x, t0_.y, t0_.z, t0_.w, t1_.x, t1_.y, t1_.z, t1_.w};\
        asm volatile("" : "+v"(V)); }

// acc(4 chains) += dot(V[0..7], h[8m..8m+7]) via two uniform b128 reads
#define HD(V, M)                                                            \
    {   const float4 ha_ = hp[2*(M)], hb_ = hp[2*(M) + 1];                  \
        a0 = fmaf(ha_.x, V[0], a0); a1 = fmaf(ha_.y, V[1], a1);             \
        a2 = fmaf(ha_.z, V[2], a2); a3 = fmaf(ha_.w, V[3], a3);             \
        a0 = fmaf(hb_.x, V[4], a0); a1 = fmaf(hb_.y, V[5], a1);             \
        a2 = fmaf(hb_.z, V[6], a2); a3 = fmaf(hb_.w, V[7], a3); }

// LDS column swizzle for the GEMM tiles
__device__ __forceinline__ int swz(int c) { return c + 4 * (c >> 5); }

// ---------------------------------------------------------------------------
// XG GEMM: XG[m][n] = dot(x[m][:], W_ih[n][:]) + bias[n]   (unchanged, R7)
// ---------------------------------------------------------------------------
__global__ __launch_bounds__(256, 2) void xg_gemm(
    const float* __restrict__ xch,    // [Mc,128] chunk of x
    const float* __restrict__ W_ih,   // [256,128]
    const float* __restrict__ bias,   // [256]
    float* __restrict__ XG)           // [Mc,256]
{
    const int tid = threadIdx.x;
    const int tx  = tid & 15;
    const int ty  = tid >> 4;
    const int mt  = blockIdx.x;
    const int nt  = blockIdx.y;

    __shared__ __align__(16) float as[32][140];
    __shared__ __align__(16) float bs[32][140];

    const int n0 = nt * 128 + tx * 8;
    float4 bia = *reinterpret_cast<const float4*>(&bias[n0]);
    float4 bib = *reinterpret_cast<const float4*>(&bias[n0 + 4]);

    float acc[8][8];
#pragma unroll
    for (int r = 0; r < 8; ++r)
#pragma unroll
        for (int cc = 0; cc < 8; ++cc) acc[r][cc] = 0.0f;

    const int srow = tid >> 3;
    const int skk  = (tid & 7) * 4;

    for (int ks = 0; ks < 4; ++ks) {
        const int k0 = ks * 32;
        __syncthreads();
#pragma unroll
        for (int i = 0; i < 4; ++i) {
            const int mr = srow + 32 * i;
            float4 xa = *reinterpret_cast<const float4*>(
                &xch[(size_t)(mt * 128 + mr) * I_SZ + k0 + skk]);
            as[skk + 0][swz(mr)] = xa.x; as[skk + 1][swz(mr)] = xa.y;
            as[skk + 2][swz(mr)] = xa.z; as[skk + 3][swz(mr)] = xa.w;
            float4 wa = *reinterpret_cast<const float4*>(
                &W_ih[(size_t)(nt * 128 + mr) * I_SZ + k0 + skk]);
            bs[skk + 0][swz(mr)] = wa.x; bs[skk + 1][swz(mr)] = wa.y;
            bs[skk + 2][swz(mr)] = wa.z; bs[skk + 3][swz(mr)] = wa.w;
        }
        __syncthreads();

#pragma unroll 8
        for (int kk = 0; kk < 32; ++kk) {
            const float4 a0 = *reinterpret_cast<const float4*>(&as[kk][swz(ty * 8)]);
            const float4 a1 = *reinterpret_cast<const float4*>(&as[kk][swz(ty * 8) + 4]);
            const float4 b0 = *reinterpret_cast<const float4*>(&bs[kk][swz(tx * 8)]);
            const float4 b1 = *reinterpret_cast<const float4*>(&bs[kk][swz(tx * 8) + 4]);
            const float av[8] = {a0.x, a0.y, a0.z, a0.w, a1.x, a1.y, a1.z, a1.w};
            const float bv[8] = {b0.x, b0.y, b0.z, b0.w, b1.x, b1.y, b1.z, b1.w};
#pragma unroll
            for (int r = 0; r < 8; ++r)
#pragma unroll
                for (int cc = 0; cc < 8; ++cc)
                    acc[r][cc] = fmaf(av[r], bv[cc], acc[r][cc]);
        }
    }

#pragma unroll
    for (int r = 0; r < 8; ++r) {
        const size_t m = (size_t)(mt * 128 + ty * 8 + r);
        float4 o0 = {acc[r][0] + bia.x, acc[r][1] + bia.y,
                     acc[r][2] + bia.z, acc[r][3] + bia.w};
        float4 o1 = {acc[r][4] + bib.x, acc[r][5] + bib.y,
                     acc[r][6] + bib.z, acc[r][7] + bib.w};
        *reinterpret_cast<float4*>(&XG[m * G_SZ + n0])     = o0;
        *reinterpret_cast<float4*>(&XG[m * G_SZ + n0 + 4]) = o1;
    }
}

// ---------------------------------------------------------------------------
// Recurrence, quad-per-unit layout. One block per batch element, 256 threads
// (4 waves). Thread t owns full gate row (g=t&3)*64 + (u=t>>2): 64 W_hh
// floats in registers, full 64-wide h-dot (16 uniform b128 LDS reads).
// The 4 gates of unit u sit in adjacent lanes -> gate exchange is 3 shfl_xor
// (no LDS), cell computed in-quad (c lives in lane g==0), and only h (64
// floats, double-buffered) crosses LDS. ONE barrier per step.
// ---------------------------------------------------------------------------
__global__ __launch_bounds__(256, 1) void lstm_rec(
    const float* __restrict__ XG,     // [TC,B,256]
    const float* __restrict__ W_hh,   // [256,64]
    float* __restrict__ h_state,      // [B,64]
    float* __restrict__ c_state,      // [B,64]
    int TC, int first)
{
    const int b = blockIdx.x;
    const int t = threadIdx.x;
    const int u = t >> 2;             // hidden unit 0..63
    const int g = t & 3;              // gate: 0=i 1=f 2=g 3=o
    const int row = (g << 6) | u;     // W_hh row

    __shared__ __align__(16) float xgl[2][SUB][G_SZ];   // 64 KB
    __shared__ __align__(16) float hsb[2][H_SZ];        // h double buffer

    // full W_hh row -> 64 pinned register floats
    const float* ur = W_hh + row * H_SZ;
    f32x8 w0, w1, w2, w3, w4, w5, w6, w7;
    LD8PIN(w0, ur)      LD8PIN(w1, ur +  8) LD8PIN(w2, ur + 16) LD8PIN(w3, ur + 24)
    LD8PIN(w4, ur + 32) LD8PIN(w5, ur + 40) LD8PIN(w6, ur + 48) LD8PIN(w7, ur + 56)

    float c = first ? 0.0f : c_state[b * H_SZ + u];     // valid in g==0 lanes
    if (t < H_SZ) hsb[0][t] = first ? 0.0f : h_state[b * H_SZ + t];

    // XG staging coords: thread stages 32 floats (8 float4) per sub-chunk
    const int tl = t >> 3;            // 0..31  (t within sub-chunk)
    const int cs = t & 7;             // 0..7   (column octet)
    {
        const float* gp = XG + ((size_t)tl * B_SZ + b) * G_SZ + cs * 32;
#pragma unroll
        for (int m = 0; m < 8; ++m)
            *reinterpret_cast<float4*>(&xgl[0][tl][cs * 32 + 4 * m]) =
                *reinterpret_cast<const float4*>(gp + 4 * m);
    }
    __syncthreads();

    const bool isg = (g == 2);
    const int nsub = TC / SUB;
    int pb = 0;
    float hlast = 0.0f;

    for (int sub = 0; sub < nsub; ++sub) {
        const int cur = sub & 1;
        if (sub + 1 < nsub) {         // stage next sub-chunk (once per 32 steps)
            const float* gp =
                XG + ((size_t)((sub + 1) * SUB + tl) * B_SZ + b) * G_SZ + cs * 32;
#pragma unroll
            for (int m = 0; m < 8; ++m)
                *reinterpret_cast<float4*>(&xgl[cur ^ 1][tl][cs * 32 + 4 * m]) =
                    *reinterpret_cast<const float4*>(gp + 4 * m);
        }

#pragma unroll 2
        for (int ts = 0; ts < SUB; ++ts) {
            const float xg = xgl[cur][ts][row];
            const float4* hp = reinterpret_cast<const float4*>(hsb[pb]);
            float a0 = xg, a1 = 0.0f, a2 = 0.0f, a3 = 0.0f;
            HD(w0, 0) HD(w1, 1) HD(w2, 2) HD(w3, 3)
            HD(w4, 4) HD(w5, 5) HD(w6, 6) HD(w7, 7)
            const float acc = (a0 + a1) + (a2 + a3);

            // branchless activation (preacts bounded, no overflow risk)
            const float arg = isg ? (-2.0f * acc) : (-acc);
            const float e = __expf(arg);
            const float r = __builtin_amdgcn_rcpf(1.0f + e);
            const float a = isg ? (1.0f - e) * r : r;

            // gather i,f,g,o into the g==0 lane of each quad (3 shfl, no LDS)
            const float f_ = __shfl_xor(a, 1, 64);   // g0 lane: f
            const float gg = __shfl_xor(a, 2, 64);   // g0 lane: g-gate
            const float o_ = __shfl_xor(f_, 2, 64);  // g0 lane: o

            c = fmaf(f_, c, a * gg);                 // valid at g==0
            hlast = o_ * fast_tanh(c);
            if (g == 0) hsb[pb ^ 1][u] = hlast;
            __syncthreads();                         // h(t) visible to all
            pb ^= 1;
        }
    }

    if (g == 0) {
        h_state[b * H_SZ + u] = hlast;
        c_state[b * H_SZ + u] = c;
    }
}

// ---------------------------------------------------------------------------
// Reverse single cell (zero init state; W_hh_r drops out) + MLP head.
// ---------------------------------------------------------------------------
__global__ __launch_bounds__(256, 1) void lstm_tail(
    const float* __restrict__ x_last,  // [B,I]
    const float* __restrict__ W_ih_r,  // [256,128]
    const float* __restrict__ b_r,     // [256]
    const float* __restrict__ h_fwd,   // [B,64]
    const float* __restrict__ fc1_w,   // [64,128]
    const float* __restrict__ fc1_b,   // [64]
    const float* __restrict__ fc2_w,   // [32,64]
    const float* __restrict__ fc2_b,   // [32]
    const float* __restrict__ fc3_w,   // [10,32]
    const float* __restrict__ fc3_b,   // [10]
    float* __restrict__ out)           // [B,10]
{
    const int b = blockIdx.x;
    const int j = threadIdx.x;

    __shared__ float xs[I_SZ];
    __shared__ float gs[G_SZ];
    __shared__ float hc[2 * H_SZ];
    __shared__ float h1[64];
    __shared__ float h2[32];

    if (j < I_SZ) xs[j] = x_last[(size_t)b * I_SZ + j];
    if (j < H_SZ) hc[j] = h_fwd[b * H_SZ + j];
    __syncthreads();

    float a0 = b_r[j], a1 = 0.0f, a2 = 0.0f, a3 = 0.0f;
    const float* wrow = W_ih_r + j * I_SZ;
#pragma unroll
    for (int kk = 0; kk < I_SZ; kk += 4) {
        float4 wv = *reinterpret_cast<const float4*>(wrow + kk);
        a0 = fmaf(xs[kk + 0], wv.x, a0);
        a1 = fmaf(xs[kk + 1], wv.y, a1);
        a2 = fmaf(xs[kk + 2], wv.z, a2);
        a3 = fmaf(xs[kk + 3], wv.w, a3);
    }
    const float acc = (a0 + a1) + (a2 + a3);
    const int gate = j >> 6;
    gs[j] = (gate == 2) ? tanhf(acc) : 1.0f / (1.0f + expf(-acc));
    __syncthreads();

    if (j < H_SZ) {
        const float cc = gs[j] * gs[2 * H_SZ + j];     // i*g (c0 = 0)
        hc[H_SZ + j] = gs[3 * H_SZ + j] * tanhf(cc);
    }
    __syncthreads();

    if (j < 64) {
        float s0 = fc1_b[j], s1 = 0.0f, s2 = 0.0f, s3 = 0.0f;
        const float* w = fc1_w + j * 128;
#pragma unroll
        for (int kk = 0; kk < 128; kk += 4) {
            float4 wv = *reinterpret_cast<const float4*>(w + kk);
            s0 = fmaf(hc[kk + 0], wv.x, s0);
            s1 = fmaf(hc[kk + 1], wv.y, s1);
            s2 = fmaf(hc[kk + 2], wv.z, s2);
            s3 = fmaf(hc[kk + 3], wv.w, s3);
        }
        h1[j] = fmaxf((s0 + s1) + (s2 + s3), 0.0f);
    }
    __syncthreads();

    if (j < 32) {
        float s0 = fc2_b[j], s1 = 0.0f, s2 = 0.0f, s3 = 0.0f;
        const float* w = fc2_w + j * 64;
#pragma unroll
        for (int kk = 0; kk < 64; kk += 4) {
            float4 wv = *reinterpret_cast<const float4*>(w + kk);
            s0 = fmaf(h1[kk + 0], wv.x, s0);
            s1 = fmaf(h1[kk + 1], wv.y, s1);
            s2 = fmaf(h1[kk + 2], wv.z, s2);
            s3 = fmaf(h1[kk + 3], wv.w, s3);
        }
        h2[j] = fmaxf((s0 + s1) + (s2 + s3), 0.0f);
    }
    __syncthreads();

    if (j < 10) {
        float s = fc3_b[j];
#pragma unroll
        for (int kk = 0; kk < 32; ++kk) s = fmaf(h2[kk], fc3_w[j * 32 + kk], s);
        out[b * 10 + j] = s;
    }
}

extern "C" void kernel_launch(void* const* d_in, const int* in_sizes, int n_in,
                              void* d_out, int out_size, void* d_ws, size_t ws_size,
                              hipStream_t stream) {
    const float* x      = (const float*)d_in[0];
    const float* W_ih_f = (const float*)d_in[1];
    const float* W_hh_f = (const float*)d_in[2];
    const float* b_f    = (const float*)d_in[3];
    const float* W_ih_r = (const float*)d_in[4];
    // d_in[5] = W_hh_r : unused (zero initial state in reverse single step)
    const float* b_r    = (const float*)d_in[6];
    const float* fc1_w  = (const float*)d_in[7];
    const float* fc1_b  = (const float*)d_in[8];
    const float* fc2_w  = (const float*)d_in[9];
    const float* fc2_b  = (const float*)d_in[10];
    const float* fc3_w  = (const float*)d_in[11];
    const float* fc3_b  = (const float*)d_in[12];
    float* out = (float*)d_out;

    // time-chunk size: largest TC whose XG buffer (+state) fits in ws
    int TC = 1024;
    while (TC > 64 &&
           (size_t)TC * B_SZ * G_SZ * 4 + 2 * B_SZ * H_SZ * 4 > ws_size)
        TC >>= 1;

    float* XG      = (float*)d_ws;
    float* h_state = (float*)((char*)d_ws + (size_t)TC * B_SZ * G_SZ * 4);
    float* c_state = h_state + B_SZ * H_SZ;

    const int NCH = T_LEN / TC;
    for (int ch = 0; ch < NCH; ++ch) {
        const float* xch = x + (size_t)ch * TC * B_SZ * I_SZ;
        hipLaunchKernelGGL(xg_gemm, dim3(TC * B_SZ / 128, 2), dim3(256), 0,
                           stream, xch, W_ih_f, b_f, XG);
        hipLaunchKernelGGL(lstm_rec, dim3(B_SZ), dim3(256), 0, stream,
                           XG, W_hh_f, h_state, c_state, TC, ch == 0 ? 1 : 0);
    }

    const float* x_last = x + (size_t)(T_LEN - 1) * B_SZ * I_SZ;
    hipLaunchKernelGGL(lstm_tail, dim3(B_SZ), dim3(256), 0, stream,
                       x_last, W_ih_r, b_r, h_state,
                       fc1_w, fc1_b, fc2_w, fc2_b, fc3_w, fc3_b, out);
}

// Round 9
// 744.265 us; speedup vs baseline: 1.0856x; 1.0856x over previous
//
#include <hip/hip_runtime.h>
#include <math.h>

#define T_LEN 1024
#define B_SZ  256
#define I_SZ  128
#define H_SZ  64
#define G_SZ  256   // 4*H
#define SUB   32    // recurrence steps per LDS-staged XG sub-chunk

typedef float f32x8 __attribute__((ext_vector_type(8)));

__device__ __forceinline__ float fast_tanh(float x) {   // safe for any |x|
    float e = __expf(-2.0f * fabsf(x));
    float r = (1.0f - e) * __builtin_amdgcn_rcpf(1.0f + e);
    return copysignf(r, x);
}

#define LD8PIN(V, P)                                                        \
    {   float4 t0_ = *reinterpret_cast<const float4*>(P);                   \
        float4 t1_ = *reinterpret_cast<const float4*>((P) + 4);             \
        V = (f32x8){t0_.x, t0_.y, t0_.z, t0_.w, t1_.x, t1_.y, t1_.z, t1_.w};\
        asm volatile("" : "+v"(V)); }

// acc(4 chains) += dot(V[0..7], h[8m..8m+7]) via two uniform b128 reads
#define HD(V, M)                                                            \
    {   const float4 ha_ = hp[2*(M)], hb_ = hp[2*(M) + 1];                  \
        a0 = fmaf(ha_.x, V[0], a0); a1 = fmaf(ha_.y, V[1], a1);             \
        a2 = fmaf(ha_.z, V[2], a2); a3 = fmaf(ha_.w, V[3], a3);             \
        a0 = fmaf(hb_.x, V[4], a0); a1 = fmaf(hb_.y, V[5], a1);             \
        a2 = fmaf(hb_.z, V[6], a2); a3 = fmaf(hb_.w, V[7], a3); }

// LDS column swizzle for the GEMM tiles
__device__ __forceinline__ int swz(int c) { return c + 4 * (c >> 5); }

// ---------------------------------------------------------------------------
// XG GEMM: XG[m][n] = dot(x[m][:], W_ih[n][:]) + bias[n]   (unchanged, R8)
// ---------------------------------------------------------------------------
__global__ __launch_bounds__(256, 2) void xg_gemm(
    const float* __restrict__ xch,    // [Mc,128] chunk of x
    const float* __restrict__ W_ih,   // [256,128]
    const float* __restrict__ bias,   // [256]
    float* __restrict__ XG)           // [Mc,256]
{
    const int tid = threadIdx.x;
    const int tx  = tid & 15;
    const int ty  = tid >> 4;
    const int mt  = blockIdx.x;
    const int nt  = blockIdx.y;

    __shared__ __align__(16) float as[32][140];
    __shared__ __align__(16) float bs[32][140];

    const int n0 = nt * 128 + tx * 8;
    float4 bia = *reinterpret_cast<const float4*>(&bias[n0]);
    float4 bib = *reinterpret_cast<const float4*>(&bias[n0 + 4]);

    float acc[8][8];
#pragma unroll
    for (int r = 0; r < 8; ++r)
#pragma unroll
        for (int cc = 0; cc < 8; ++cc) acc[r][cc] = 0.0f;

    const int srow = tid >> 3;
    const int skk  = (tid & 7) * 4;

    for (int ks = 0; ks < 4; ++ks) {
        const int k0 = ks * 32;
        __syncthreads();
#pragma unroll
        for (int i = 0; i < 4; ++i) {
            const int mr = srow + 32 * i;
            float4 xa = *reinterpret_cast<const float4*>(
                &xch[(size_t)(mt * 128 + mr) * I_SZ + k0 + skk]);
            as[skk + 0][swz(mr)] = xa.x; as[skk + 1][swz(mr)] = xa.y;
            as[skk + 2][swz(mr)] = xa.z; as[skk + 3][swz(mr)] = xa.w;
            float4 wa = *reinterpret_cast<const float4*>(
                &W_ih[(size_t)(nt * 128 + mr) * I_SZ + k0 + skk]);
            bs[skk + 0][swz(mr)] = wa.x; bs[skk + 1][swz(mr)] = wa.y;
            bs[skk + 2][swz(mr)] = wa.z; bs[skk + 3][swz(mr)] = wa.w;
        }
        __syncthreads();

#pragma unroll 8
        for (int kk = 0; kk < 32; ++kk) {
            const float4 a0 = *reinterpret_cast<const float4*>(&as[kk][swz(ty * 8)]);
            const float4 a1 = *reinterpret_cast<const float4*>(&as[kk][swz(ty * 8) + 4]);
            const float4 b0 = *reinterpret_cast<const float4*>(&bs[kk][swz(tx * 8)]);
            const float4 b1 = *reinterpret_cast<const float4*>(&bs[kk][swz(tx * 8) + 4]);
            const float av[8] = {a0.x, a0.y, a0.z, a0.w, a1.x, a1.y, a1.z, a1.w};
            const float bv[8] = {b0.x, b0.y, b0.z, b0.w, b1.x, b1.y, b1.z, b1.w};
#pragma unroll
            for (int r = 0; r < 8; ++r)
#pragma unroll
                for (int cc = 0; cc < 8; ++cc)
                    acc[r][cc] = fmaf(av[r], bv[cc], acc[r][cc]);
        }
    }

#pragma unroll
    for (int r = 0; r < 8; ++r) {
        const size_t m = (size_t)(mt * 128 + ty * 8 + r);
        float4 o0 = {acc[r][0] + bia.x, acc[r][1] + bia.y,
                     acc[r][2] + bia.z, acc[r][3] + bia.w};
        float4 o1 = {acc[r][4] + bib.x, acc[r][5] + bib.y,
                     acc[r][6] + bib.z, acc[r][7] + bib.w};
        *reinterpret_cast<float4*>(&XG[m * G_SZ + n0])     = o0;
        *reinterpret_cast<float4*>(&XG[m * G_SZ + n0 + 4]) = o1;
    }
}

// ---------------------------------------------------------------------------
// Recurrence: 512 threads (8 waves, 2/SIMD), quad-gate + half split.
// Thread (u = t>>3, g = (t>>1)&3, half = t&1) computes half of gate row
// (g*64+u)'s h-dot with 32 register-resident W_hh floats.
//   half-combine: shfl_xor(1); gate exchange: shfl_xor(2), shfl_xor(4).
// Cell update in-quad (no LDS for gates); only h crosses LDS. ONE barrier
// per step. XG staged per 32 steps via flat coalesced copy (conflict-free).
// ---------------------------------------------------------------------------
__global__ __launch_bounds__(512, 1) void lstm_rec(
    const float* __restrict__ XG,     // [TC,B,256]
    const float* __restrict__ W_hh,   // [256,64]
    float* __restrict__ h_state,      // [B,64]
    float* __restrict__ c_state,      // [B,64]
    int TC, int first)
{
    const int b    = blockIdx.x;
    const int t    = threadIdx.x;
    const int half = t & 1;
    const int g    = (t >> 1) & 3;    // gate: 0=i 1=f 2=g 3=o
    const int u    = t >> 3;          // hidden unit 0..63
    const int row  = (g << 6) | u;    // gate-vector index

    __shared__ __align__(16) float xgl[2][SUB][G_SZ];   // 64 KB
    __shared__ __align__(16) float hsb[2][H_SZ];        // h double buffer

    // half W_hh row -> 32 pinned register floats (proven resident in R7)
    const float* ur = W_hh + row * H_SZ + half * 32;
    f32x8 w0, w1, w2, w3;
    LD8PIN(w0, ur) LD8PIN(w1, ur + 8) LD8PIN(w2, ur + 16) LD8PIN(w3, ur + 24)

    float c = first ? 0.0f : c_state[b * H_SZ + u];
    if (t < H_SZ) hsb[0][t] = first ? 0.0f : h_state[b * H_SZ + t];

    // stage sub-chunk 0: flat copy; thread t copies float4 #(t+512i).
    // LDS banks cycle (conflict-free); global contiguous 1KB per wave.
    {
        float* xf = &xgl[0][0][0];
#pragma unroll
        for (int i = 0; i < 4; ++i) {
            const int F = t + 512 * i;            // float4 index 0..2047
            const int r = F >> 6, cw = F & 63;    // step row, float4 col
            *reinterpret_cast<float4*>(xf + 4 * F) =
                *reinterpret_cast<const float4*>(
                    XG + ((size_t)r * B_SZ + b) * G_SZ + 4 * cw);
        }
    }
    __syncthreads();

    const bool isg = (g == 2);
    const int nsub = TC / SUB;
    int pb = 0;
    float hlast = 0.0f;

    for (int sub = 0; sub < nsub; ++sub) {
        const int cur = sub & 1;
        if (sub + 1 < nsub) {         // stage next sub-chunk (flat copy)
            float* xf = &xgl[cur ^ 1][0][0];
#pragma unroll
            for (int i = 0; i < 4; ++i) {
                const int F = t + 512 * i;
                const int r = (F >> 6) + (sub + 1) * SUB, cw = F & 63;
                *reinterpret_cast<float4*>(xf + 4 * F) =
                    *reinterpret_cast<const float4*>(
                        XG + ((size_t)r * B_SZ + b) * G_SZ + 4 * cw);
            }
        }

#pragma unroll 4
        for (int ts = 0; ts < SUB; ++ts) {
            const float xg = xgl[cur][ts][row];           // 4-way, single b32
            const float4* hp =
                reinterpret_cast<const float4*>(&hsb[pb][half * 32]);
            float a0 = 0.0f, a1 = 0.0f, a2 = 0.0f, a3 = 0.0f;
            HD(w0, 0) HD(w1, 1) HD(w2, 2) HD(w3, 3)
            float acc = (a0 + a1) + (a2 + a3);
            acc += __shfl_xor(acc, 1, 64);                // combine halves
            acc += xg;

            // branchless activation (preacts bounded; no overflow risk)
            const float arg = isg ? (-2.0f * acc) : (-acc);
            const float e = __expf(arg);
            const float r = __builtin_amdgcn_rcpf(1.0f + e);
            const float a = isg ? (1.0f - e) * r : r;

            // gather f,g,o into g==0 lanes (gate index = lane bits [1:2])
            const float f_ = __shfl_xor(a, 2, 64);        // gate g^1
            const float gg = __shfl_xor(a, 4, 64);        // gate g^2
            const float o_ = __shfl_xor(f_, 4, 64);       // gate g^3

            c = fmaf(f_, c, a * gg);                      // valid at g==0
            hlast = o_ * fast_tanh(c);
            if ((t & 7) == 0) hsb[pb ^ 1][u] = hlast;     // one lane per unit
            __syncthreads();                              // h(t) visible
            pb ^= 1;
        }
    }

    if ((t & 7) == 0) {
        h_state[b * H_SZ + u] = hlast;
        c_state[b * H_SZ + u] = c;
    }
}

// ---------------------------------------------------------------------------
// Reverse single cell (zero init state; W_hh_r drops out) + MLP head.
// ---------------------------------------------------------------------------
__global__ __launch_bounds__(256, 1) void lstm_tail(
    const float* __restrict__ x_last,  // [B,I]
    const float* __restrict__ W_ih_r,  // [256,128]
    const float* __restrict__ b_r,     // [256]
    const float* __restrict__ h_fwd,   // [B,64]
    const float* __restrict__ fc1_w,   // [64,128]
    const float* __restrict__ fc1_b,   // [64]
    const float* __restrict__ fc2_w,   // [32,64]
    const float* __restrict__ fc2_b,   // [32]
    const float* __restrict__ fc3_w,   // [10,32]
    const float* __restrict__ fc3_b,   // [10]
    float* __restrict__ out)           // [B,10]
{
    const int b = blockIdx.x;
    const int j = threadIdx.x;

    __shared__ float xs[I_SZ];
    __shared__ float gs[G_SZ];
    __shared__ float hc[2 * H_SZ];
    __shared__ float h1[64];
    __shared__ float h2[32];

    if (j < I_SZ) xs[j] = x_last[(size_t)b * I_SZ + j];
    if (j < H_SZ) hc[j] = h_fwd[b * H_SZ + j];
    __syncthreads();

    float a0 = b_r[j], a1 = 0.0f, a2 = 0.0f, a3 = 0.0f;
    const float* wrow = W_ih_r + j * I_SZ;
#pragma unroll
    for (int kk = 0; kk < I_SZ; kk += 4) {
        float4 wv = *reinterpret_cast<const float4*>(wrow + kk);
        a0 = fmaf(xs[kk + 0], wv.x, a0);
        a1 = fmaf(xs[kk + 1], wv.y, a1);
        a2 = fmaf(xs[kk + 2], wv.z, a2);
        a3 = fmaf(xs[kk + 3], wv.w, a3);
    }
    const float acc = (a0 + a1) + (a2 + a3);
    const int gate = j >> 6;
    gs[j] = (gate == 2) ? tanhf(acc) : 1.0f / (1.0f + expf(-acc));
    __syncthreads();

    if (j < H_SZ) {
        const float cc = gs[j] * gs[2 * H_SZ + j];     // i*g (c0 = 0)
        hc[H_SZ + j] = gs[3 * H_SZ + j] * tanhf(cc);
    }
    __syncthreads();

    if (j < 64) {
        float s0 = fc1_b[j], s1 = 0.0f, s2 = 0.0f, s3 = 0.0f;
        const float* w = fc1_w + j * 128;
#pragma unroll
        for (int kk = 0; kk < 128; kk += 4) {
            float4 wv = *reinterpret_cast<const float4*>(w + kk);
            s0 = fmaf(hc[kk + 0], wv.x, s0);
            s1 = fmaf(hc[kk + 1], wv.y, s1);
            s2 = fmaf(hc[kk + 2], wv.z, s2);
            s3 = fmaf(hc[kk + 3], wv.w, s3);
        }
        h1[j] = fmaxf((s0 + s1) + (s2 + s3), 0.0f);
    }
    __syncthreads();

    if (j < 32) {
        float s0 = fc2_b[j], s1 = 0.0f, s2 = 0.0f, s3 = 0.0f;
        const float* w = fc2_w + j * 64;
#pragma unroll
        for (int kk = 0; kk < 64; kk += 4) {
            float4 wv = *reinterpret_cast<const float4*>(w + kk);
            s0 = fmaf(h1[kk + 0], wv.x, s0);
            s1 = fmaf(h1[kk + 1], wv.y, s1);
            s2 = fmaf(h1[kk + 2], wv.z, s2);
            s3 = fmaf(h1[kk + 3], wv.w, s3);
        }
        h2[j] = fmaxf((s0 + s1) + (s2 + s3), 0.0f);
    }
    __syncthreads();

    if (j < 10) {
        float s = fc3_b[j];
#pragma unroll
        for (int kk = 0; kk < 32; ++kk) s = fmaf(h2[kk], fc3_w[j * 32 + kk], s);
        out[b * 10 + j] = s;
    }
}

extern "C" void kernel_launch(void* const* d_in, const int* in_sizes, int n_in,
                              void* d_out, int out_size, void* d_ws, size_t ws_size,
                              hipStream_t stream) {
    const float* x      = (const float*)d_in[0];
    const float* W_ih_f = (const float*)d_in[1];
    const float* W_hh_f = (const float*)d_in[2];
    const float* b_f    = (const float*)d_in[3];
    const float* W_ih_r = (const float*)d_in[4];
    // d_in[5] = W_hh_r : unused (zero initial state in reverse single step)
    const float* b_r    = (const float*)d_in[6];
    const float* fc1_w  = (const float*)d_in[7];
    const float* fc1_b  = (const float*)d_in[8];
    const float* fc2_w  = (const float*)d_in[9];
    const float* fc2_b  = (const float*)d_in[10];
    const float* fc3_w  = (const float*)d_in[11];
    const float* fc3_b  = (const float*)d_in[12];
    float* out = (float*)d_out;

    // time-chunk size: largest TC whose XG buffer (+state) fits in ws
    int TC = 1024;
    while (TC > 64 &&
           (size_t)TC * B_SZ * G_SZ * 4 + 2 * B_SZ * H_SZ * 4 > ws_size)
        TC >>= 1;

    float* XG      = (float*)d_ws;
    float* h_state = (float*)((char*)d_ws + (size_t)TC * B_SZ * G_SZ * 4);
    float* c_state = h_state + B_SZ * H_SZ;

    const int NCH = T_LEN / TC;
    for (int ch = 0; ch < NCH; ++ch) {
        const float* xch = x + (size_t)ch * TC * B_SZ * I_SZ;
        hipLaunchKernelGGL(xg_gemm, dim3(TC * B_SZ / 128, 2), dim3(256), 0,
                           stream, xch, W_ih_f, b_f, XG);
        hipLaunchKernelGGL(lstm_rec, dim3(B_SZ), dim3(512), 0, stream,
                           XG, W_hh_f, h_state, c_state, TC, ch == 0 ? 1 : 0);
    }

    const float* x_last = x + (size_t)(T_LEN - 1) * B_SZ * I_SZ;
    hipLaunchKernelGGL(lstm_tail, dim3(B_SZ), dim3(256), 0, stream,
                       x_last, W_ih_r, b_r, h_state,
                       fc1_w, fc1_b, fc2_w, fc2_b, fc3_w, fc3_b, out);
}

// Round 10
// 685.830 us; speedup vs baseline: 1.1781x; 1.0852x over previous
//
#include <hip/hip_runtime.h>
#include <math.h>

#define T_LEN 1024
#define B_SZ  256
#define I_SZ  128
#define H_SZ  64
#define G_SZ  256   // 4*H
#define SUB   32    // recurrence steps per LDS-staged XG sub-chunk

typedef float f32x8 __attribute__((ext_vector_type(8)));

__device__ __forceinline__ float fast_tanh(float x) {   // safe for any |x|
    float e = __expf(-2.0f * fabsf(x));
    float r = (1.0f - e) * __builtin_amdgcn_rcpf(1.0f + e);
    return copysignf(r, x);
}

#define LD8PIN(V, P)                                                        \
    {   float4 t0_ = *reinterpret_cast<const float4*>(P);                   \
        float4 t1_ = *reinterpret_cast<const float4*>((P) + 4);             \
        V = (f32x8){t0_.x, t0_.y, t0_.z, t0_.w, t1_.x, t1_.y, t1_.z, t1_.w};\
        asm volatile("" : "+v"(V)); }

// acc(4 chains) += dot(V[0..7], h[8m..8m+7]) via two uniform b128 reads
#define HD(V, M)                                                            \
    {   const float4 ha_ = hp[2*(M)], hb_ = hp[2*(M) + 1];                  \
        a0 = fmaf(ha_.x, V[0], a0); a1 = fmaf(ha_.y, V[1], a1);             \
        a2 = fmaf(ha_.z, V[2], a2); a3 = fmaf(ha_.w, V[3], a3);             \
        a0 = fmaf(hb_.x, V[4], a0); a1 = fmaf(hb_.y, V[5], a1);             \
        a2 = fmaf(hb_.z, V[6], a2); a3 = fmaf(hb_.w, V[7], a3); }

// LDS column swizzle for the GEMM tiles
__device__ __forceinline__ int swz(int c) { return c + 4 * (c >> 5); }

// ---------------------------------------------------------------------------
// XG GEMM: XG[m][n] = dot(x[m][:], W_ih[n][:]) + bias[n]   (unchanged, R9)
// ---------------------------------------------------------------------------
__global__ __launch_bounds__(256, 2) void xg_gemm(
    const float* __restrict__ xch,    // [Mc,128] chunk of x
    const float* __restrict__ W_ih,   // [256,128]
    const float* __restrict__ bias,   // [256]
    float* __restrict__ XG)           // [Mc,256]
{
    const int tid = threadIdx.x;
    const int tx  = tid & 15;
    const int ty  = tid >> 4;
    const int mt  = blockIdx.x;
    const int nt  = blockIdx.y;

    __shared__ __align__(16) float as[32][140];
    __shared__ __align__(16) float bs[32][140];

    const int n0 = nt * 128 + tx * 8;
    float4 bia = *reinterpret_cast<const float4*>(&bias[n0]);
    float4 bib = *reinterpret_cast<const float4*>(&bias[n0 + 4]);

    float acc[8][8];
#pragma unroll
    for (int r = 0; r < 8; ++r)
#pragma unroll
        for (int cc = 0; cc < 8; ++cc) acc[r][cc] = 0.0f;

    const int srow = tid >> 3;
    const int skk  = (tid & 7) * 4;

    for (int ks = 0; ks < 4; ++ks) {
        const int k0 = ks * 32;
        __syncthreads();
#pragma unroll
        for (int i = 0; i < 4; ++i) {
            const int mr = srow + 32 * i;
            float4 xa = *reinterpret_cast<const float4*>(
                &xch[(size_t)(mt * 128 + mr) * I_SZ + k0 + skk]);
            as[skk + 0][swz(mr)] = xa.x; as[skk + 1][swz(mr)] = xa.y;
            as[skk + 2][swz(mr)] = xa.z; as[skk + 3][swz(mr)] = xa.w;
            float4 wa = *reinterpret_cast<const float4*>(
                &W_ih[(size_t)(nt * 128 + mr) * I_SZ + k0 + skk]);
            bs[skk + 0][swz(mr)] = wa.x; bs[skk + 1][swz(mr)] = wa.y;
            bs[skk + 2][swz(mr)] = wa.z; bs[skk + 3][swz(mr)] = wa.w;
        }
        __syncthreads();

#pragma unroll 8
        for (int kk = 0; kk < 32; ++kk) {
            const float4 a0 = *reinterpret_cast<const float4*>(&as[kk][swz(ty * 8)]);
            const float4 a1 = *reinterpret_cast<const float4*>(&as[kk][swz(ty * 8) + 4]);
            const float4 b0 = *reinterpret_cast<const float4*>(&bs[kk][swz(tx * 8)]);
            const float4 b1 = *reinterpret_cast<const float4*>(&bs[kk][swz(tx * 8) + 4]);
            const float av[8] = {a0.x, a0.y, a0.z, a0.w, a1.x, a1.y, a1.z, a1.w};
            const float bv[8] = {b0.x, b0.y, b0.z, b0.w, b1.x, b1.y, b1.z, b1.w};
#pragma unroll
            for (int r = 0; r < 8; ++r)
#pragma unroll
                for (int cc = 0; cc < 8; ++cc)
                    acc[r][cc] = fmaf(av[r], bv[cc], acc[r][cc]);
        }
    }

#pragma unroll
    for (int r = 0; r < 8; ++r) {
        const size_t m = (size_t)(mt * 128 + ty * 8 + r);
        float4 o0 = {acc[r][0] + bia.x, acc[r][1] + bia.y,
                     acc[r][2] + bia.z, acc[r][3] + bia.w};
        float4 o1 = {acc[r][4] + bib.x, acc[r][5] + bib.y,
                     acc[r][6] + bib.z, acc[r][7] + bib.w};
        *reinterpret_cast<float4*>(&XG[m * G_SZ + n0])     = o0;
        *reinterpret_cast<float4*>(&XG[m * G_SZ + n0 + 4]) = o1;
    }
}

// ---------------------------------------------------------------------------
// Recurrence, conflict-free mapping + replicated cell. 512 threads (8 waves).
// Thread t owns HALF of gate row (row = t>>1, half = t&1): a wave covers 32
// CONSECUTIVE rows, so the per-step xg read xgl[ts][row] hits banks 0..31
// (2-way broadcast pairs) with a LINEAR layout — zero conflicts, no shfl
// gate exchange. Gates go through gs (double-buffered, 1 barrier/step);
// the cell update is REPLICATED: lane l of every wave computes unit l's
// (c,h) identically and writes its own wave's h copy hsb[w][l] — the next
// step's h-dot reads the wave's own copy (lgkmcnt-ordered, no 2nd barrier).
// ---------------------------------------------------------------------------
__global__ __launch_bounds__(512, 1) void lstm_rec(
    const float* __restrict__ XG,     // [TC,B,256]
    const float* __restrict__ W_hh,   // [256,64]
    float* __restrict__ h_state,      // [B,64]
    float* __restrict__ c_state,      // [B,64]
    int TC, int first)
{
    const int b    = blockIdx.x;
    const int t    = threadIdx.x;
    const int row  = t >> 1;          // gate row 0..255 (wave-consecutive)
    const int half = t & 1;
    const int g    = row >> 6;        // wave-uniform gate id
    const int w    = t >> 6;          // wave 0..7
    const int l    = t & 63;          // lane 0..63 (= unit for cell phase)

    __shared__ __align__(16) float xgl[2][SUB][G_SZ];   // 64 KB
    __shared__ __align__(16) float hsb[8][H_SZ];        // per-wave h copies
    __shared__ float gs[2][G_SZ];                       // double-buffered gates

    // half W_hh row -> 32 pinned register floats (proven resident R7/R9)
    const float* ur = W_hh + row * H_SZ + half * 32;
    f32x8 w0, w1, w2, w3;
    LD8PIN(w0, ur) LD8PIN(w1, ur + 8) LD8PIN(w2, ur + 16) LD8PIN(w3, ur + 24)

    // replicated state: lane l of every wave carries c[l]; own h copy in LDS
    float c = first ? 0.0f : c_state[b * H_SZ + l];
    hsb[w][l] = first ? 0.0f : h_state[b * H_SZ + l];

    // stage sub-chunk 0: flat coalesced copy (thread t copies float4 #t+512i)
    {
        float* xf = &xgl[0][0][0];
#pragma unroll
        for (int i = 0; i < 4; ++i) {
            const int F = t + 512 * i;            // float4 index 0..2047
            const int r = F >> 6, cw = F & 63;    // step row, float4 col
            *reinterpret_cast<float4*>(xf + 4 * F) =
                *reinterpret_cast<const float4*>(
                    XG + ((size_t)r * B_SZ + b) * G_SZ + 4 * cw);
        }
    }
    __syncthreads();

    const bool isg = (g == 2);
    const int nsub = TC / SUB;
    int db = 0;
    float h = 0.0f;

    for (int sub = 0; sub < nsub; ++sub) {
        const int cur = sub & 1;
        if (sub + 1 < nsub) {         // stage next sub-chunk (flat copy)
            float* xf = &xgl[cur ^ 1][0][0];
#pragma unroll
            for (int i = 0; i < 4; ++i) {
                const int F = t + 512 * i;
                const int r = (F >> 6) + (sub + 1) * SUB, cw = F & 63;
                *reinterpret_cast<float4*>(xf + 4 * F) =
                    *reinterpret_cast<const float4*>(
                        XG + ((size_t)r * B_SZ + b) * G_SZ + 4 * cw);
            }
        }

#pragma unroll 4
        for (int ts = 0; ts < SUB; ++ts) {
            // xg read: lane l -> row 32w+(l>>1): banks 0..31, 2-way bcast, free
            const float xg = xgl[cur][ts][row];
            // h-dot: 8 wave-uniform broadcast b128 reads of OWN wave's h copy
            const float4* hp =
                reinterpret_cast<const float4*>(&hsb[w][half * 32]);
            float a0 = 0.0f, a1 = 0.0f, a2 = 0.0f, a3 = 0.0f;
            HD(w0, 0) HD(w1, 1) HD(w2, 2) HD(w3, 3)
            float acc = (a0 + a1) + (a2 + a3);
            acc += __shfl_xor(acc, 1, 64);                // combine halves
            acc += xg;

            // activation (gate wave-uniform; branchless select)
            const float arg = isg ? (-2.0f * acc) : (-acc);
            const float e = __expf(arg);
            const float r = __builtin_amdgcn_rcpf(1.0f + e);
            const float a = isg ? (1.0f - e) * r : r;

            if (half == 0) gs[db][row] = a;   // banks 0..31, conflict-free
            __syncthreads();                  // gates visible

            // replicated cell update: lane l handles unit l (4 free b32 reads)
            const float ig = gs[db][l];
            const float fg = gs[db][H_SZ + l];
            const float gg = gs[db][2 * H_SZ + l];
            const float og = gs[db][3 * H_SZ + l];
            c = fmaf(fg, c, ig * gg);
            h = og * fast_tanh(c);
            hsb[w][l] = h;                    // own-wave copy: no 2nd barrier
            db ^= 1;
        }
    }

    if (t < H_SZ) {                           // wave 0 writes final state
        h_state[b * H_SZ + t] = h;
        c_state[b * H_SZ + t] = c;
    }
}

// ---------------------------------------------------------------------------
// Reverse single cell (zero init state; W_hh_r drops out) + MLP head.
// ---------------------------------------------------------------------------
__global__ __launch_bounds__(256, 1) void lstm_tail(
    const float* __restrict__ x_last,  // [B,I]
    const float* __restrict__ W_ih_r,  // [256,128]
    const float* __restrict__ b_r,     // [256]
    const float* __restrict__ h_fwd,   // [B,64]
    const float* __restrict__ fc1_w,   // [64,128]
    const float* __restrict__ fc1_b,   // [64]
    const float* __restrict__ fc2_w,   // [32,64]
    const float* __restrict__ fc2_b,   // [32]
    const float* __restrict__ fc3_w,   // [10,32]
    const float* __restrict__ fc3_b,   // [10]
    float* __restrict__ out)           // [B,10]
{
    const int b = blockIdx.x;
    const int j = threadIdx.x;

    __shared__ float xs[I_SZ];
    __shared__ float gs[G_SZ];
    __shared__ float hc[2 * H_SZ];
    __shared__ float h1[64];
    __shared__ float h2[32];

    if (j < I_SZ) xs[j] = x_last[(size_t)b * I_SZ + j];
    if (j < H_SZ) hc[j] = h_fwd[b * H_SZ + j];
    __syncthreads();

    float a0 = b_r[j], a1 = 0.0f, a2 = 0.0f, a3 = 0.0f;
    const float* wrow = W_ih_r + j * I_SZ;
#pragma unroll
    for (int kk = 0; kk < I_SZ; kk += 4) {
        float4 wv = *reinterpret_cast<const float4*>(wrow + kk);
        a0 = fmaf(xs[kk + 0], wv.x, a0);
        a1 = fmaf(xs[kk + 1], wv.y, a1);
        a2 = fmaf(xs[kk + 2], wv.z, a2);
        a3 = fmaf(xs[kk + 3], wv.w, a3);
    }
    const float acc = (a0 + a1) + (a2 + a3);
    const int gate = j >> 6;
    gs[j] = (gate == 2) ? tanhf(acc) : 1.0f / (1.0f + expf(-acc));
    __syncthreads();

    if (j < H_SZ) {
        const float cc = gs[j] * gs[2 * H_SZ + j];     // i*g (c0 = 0)
        hc[H_SZ + j] = gs[3 * H_SZ + j] * tanhf(cc);
    }
    __syncthreads();

    if (j < 64) {
        float s0 = fc1_b[j], s1 = 0.0f, s2 = 0.0f, s3 = 0.0f;
        const float* w = fc1_w + j * 128;
#pragma unroll
    for (int kk = 0; kk < 128; kk += 4) {
            float4 wv = *reinterpret_cast<const float4*>(w + kk);
            s0 = fmaf(hc[kk + 0], wv.x, s0);
            s1 = fmaf(hc[kk + 1], wv.y, s1);
            s2 = fmaf(hc[kk + 2], wv.z, s2);
            s3 = fmaf(hc[kk + 3], wv.w, s3);
        }
        h1[j] = fmaxf((s0 + s1) + (s2 + s3), 0.0f);
    }
    __syncthreads();

    if (j < 32) {
        float s0 = fc2_b[j], s1 = 0.0f, s2 = 0.0f, s3 = 0.0f;
        const float* w = fc2_w + j * 64;
#pragma unroll
        for (int kk = 0; kk < 64; kk += 4) {
            float4 wv = *reinterpret_cast<const float4*>(w + kk);
            s0 = fmaf(h1[kk + 0], wv.x, s0);
            s1 = fmaf(h1[kk + 1], wv.y, s1);
            s2 = fmaf(h1[kk + 2], wv.z, s2);
            s3 = fmaf(h1[kk + 3], wv.w, s3);
        }
        h2[j] = fmaxf((s0 + s1) + (s2 + s3), 0.0f);
    }
    __syncthreads();

    if (j < 10) {
        float s = fc3_b[j];
#pragma unroll
        for (int kk = 0; kk < 32; ++kk) s = fmaf(h2[kk], fc3_w[j * 32 + kk], s);
        out[b * 10 + j] = s;
    }
}

extern "C" void kernel_launch(void* const* d_in, const int* in_sizes, int n_in,
                              void* d_out, int out_size, void* d_ws, size_t ws_size,
                              hipStream_t stream) {
    const float* x      = (const float*)d_in[0];
    const float* W_ih_f = (const float*)d_in[1];
    const float* W_hh_f = (const float*)d_in[2];
    const float* b_f    = (const float*)d_in[3];
    const float* W_ih_r = (const float*)d_in[4];
    // d_in[5] = W_hh_r : unused (zero initial state in reverse single step)
    const float* b_r    = (const float*)d_in[6];
    const float* fc1_w  = (const float*)d_in[7];
    const float* fc1_b  = (const float*)d_in[8];
    const float* fc2_w  = (const float*)d_in[9];
    const float* fc2_b  = (const float*)d_in[10];
    const float* fc3_w  = (const float*)d_in[11];
    const float* fc3_b  = (const float*)d_in[12];
    float* out = (float*)d_out;

    // time-chunk size: largest TC whose XG buffer (+state) fits in ws
    int TC = 1024;
    while (TC > 64 &&
           (size_t)TC * B_SZ * G_SZ * 4 + 2 * B_SZ * H_SZ * 4 > ws_size)
        TC >>= 1;

    float* XG      = (float*)d_ws;
    float* h_state = (float*)((char*)d_ws + (size_t)TC * B_SZ * G_SZ * 4);
    float* c_state = h_state + B_SZ * H_SZ;

    const int NCH = T_LEN / TC;
    for (int ch = 0; ch < NCH; ++ch) {
        const float* xch = x + (size_t)ch * TC * B_SZ * I_SZ;
        hipLaunchKernelGGL(xg_gemm, dim3(TC * B_SZ / 128, 2), dim3(256), 0,
                           stream, xch, W_ih_f, b_f, XG);
        hipLaunchKernelGGL(lstm_rec, dim3(B_SZ), dim3(512), 0, stream,
                           XG, W_hh_f, h_state, c_state, TC, ch == 0 ? 1 : 0);
    }

    const float* x_last = x + (size_t)(T_LEN - 1) * B_SZ * I_SZ;
    hipLaunchKernelGGL(lstm_tail, dim3(B_SZ), dim3(256), 0, stream,
                       x_last, W_ih_r, b_r, h_state,
                       fc1_w, fc1_b, fc2_w, fc2_b, fc3_w, fc3_b, out);
}

// Round 11
// 644.958 us; speedup vs baseline: 1.2528x; 1.0634x over previous
//
#include <hip/hip_runtime.h>
#include <math.h>

#define T_LEN 1024
#define B_SZ  256
#define I_SZ  128
#define H_SZ  64
#define G_SZ  256   // 4*H
#define SUB   32    // recurrence steps per LDS-staged XG sub-chunk

typedef float f32x8 __attribute__((ext_vector_type(8)));

__device__ __forceinline__ float fast_tanh(float x) {   // safe for any |x|
    float e = __expf(-2.0f * fabsf(x));
    float r = (1.0f - e) * __builtin_amdgcn_rcpf(1.0f + e);
    return copysignf(r, x);
}

#define LD8PIN(V, P)                                                        \
    {   float4 t0_ = *reinterpret_cast<const float4*>(P);                   \
        float4 t1_ = *reinterpret_cast<const float4*>((P) + 4);             \
        V = (f32x8){t0_.x, t0_.y, t0_.z, t0_.w, t1_.x, t1_.y, t1_.z, t1_.w};\
        asm volatile("" : "+v"(V)); }

// acc(4 chains) += h[K..K+7]*V[0..7], h fetched cross-lane via v_readlane
// (VALU pipe, zero LDS traffic; SGPR folds directly into v_fma).
#define RL8(V, K)                                                           \
    {   unsigned r0_ = __builtin_amdgcn_readlane(hu, (K) + 0);              \
        unsigned r1_ = __builtin_amdgcn_readlane(hu, (K) + 1);              \
        unsigned r2_ = __builtin_amdgcn_readlane(hu, (K) + 2);              \
        unsigned r3_ = __builtin_amdgcn_readlane(hu, (K) + 3);              \
        a0 = fmaf(__uint_as_float(r0_), V[0], a0);                          \
        a1 = fmaf(__uint_as_float(r1_), V[1], a1);                          \
        a2 = fmaf(__uint_as_float(r2_), V[2], a2);                          \
        a3 = fmaf(__uint_as_float(r3_), V[3], a3);                          \
        unsigned r4_ = __builtin_amdgcn_readlane(hu, (K) + 4);              \
        unsigned r5_ = __builtin_amdgcn_readlane(hu, (K) + 5);              \
        unsigned r6_ = __builtin_amdgcn_readlane(hu, (K) + 6);              \
        unsigned r7_ = __builtin_amdgcn_readlane(hu, (K) + 7);              \
        a0 = fmaf(__uint_as_float(r4_), V[4], a0);                          \
        a1 = fmaf(__uint_as_float(r5_), V[5], a1);                          \
        a2 = fmaf(__uint_as_float(r6_), V[6], a2);                          \
        a3 = fmaf(__uint_as_float(r7_), V[7], a3); }

// LDS column swizzle for the GEMM tiles
__device__ __forceinline__ int swz(int c) { return c + 4 * (c >> 5); }

// ---------------------------------------------------------------------------
// XG GEMM: XG[m][n] = dot(x[m][:], W_ih[n][:]) + bias[n]   (unchanged, R10)
// ---------------------------------------------------------------------------
__global__ __launch_bounds__(256, 2) void xg_gemm(
    const float* __restrict__ xch,    // [Mc,128] chunk of x
    const float* __restrict__ W_ih,   // [256,128]
    const float* __restrict__ bias,   // [256]
    float* __restrict__ XG)           // [Mc,256]
{
    const int tid = threadIdx.x;
    const int tx  = tid & 15;
    const int ty  = tid >> 4;
    const int mt  = blockIdx.x;
    const int nt  = blockIdx.y;

    __shared__ __align__(16) float as[32][140];
    __shared__ __align__(16) float bs[32][140];

    const int n0 = nt * 128 + tx * 8;
    float4 bia = *reinterpret_cast<const float4*>(&bias[n0]);
    float4 bib = *reinterpret_cast<const float4*>(&bias[n0 + 4]);

    float acc[8][8];
#pragma unroll
    for (int r = 0; r < 8; ++r)
#pragma unroll
        for (int cc = 0; cc < 8; ++cc) acc[r][cc] = 0.0f;

    const int srow = tid >> 3;
    const int skk  = (tid & 7) * 4;

    for (int ks = 0; ks < 4; ++ks) {
        const int k0 = ks * 32;
        __syncthreads();
#pragma unroll
        for (int i = 0; i < 4; ++i) {
            const int mr = srow + 32 * i;
            float4 xa = *reinterpret_cast<const float4*>(
                &xch[(size_t)(mt * 128 + mr) * I_SZ + k0 + skk]);
            as[skk + 0][swz(mr)] = xa.x; as[skk + 1][swz(mr)] = xa.y;
            as[skk + 2][swz(mr)] = xa.z; as[skk + 3][swz(mr)] = xa.w;
            float4 wa = *reinterpret_cast<const float4*>(
                &W_ih[(size_t)(nt * 128 + mr) * I_SZ + k0 + skk]);
            bs[skk + 0][swz(mr)] = wa.x; bs[skk + 1][swz(mr)] = wa.y;
            bs[skk + 2][swz(mr)] = wa.z; bs[skk + 3][swz(mr)] = wa.w;
        }
        __syncthreads();

#pragma unroll 8
        for (int kk = 0; kk < 32; ++kk) {
            const float4 a0 = *reinterpret_cast<const float4*>(&as[kk][swz(ty * 8)]);
            const float4 a1 = *reinterpret_cast<const float4*>(&as[kk][swz(ty * 8) + 4]);
            const float4 b0 = *reinterpret_cast<const float4*>(&bs[kk][swz(tx * 8)]);
            const float4 b1 = *reinterpret_cast<const float4*>(&bs[kk][swz(tx * 8) + 4]);
            const float av[8] = {a0.x, a0.y, a0.z, a0.w, a1.x, a1.y, a1.z, a1.w};
            const float bv[8] = {b0.x, b0.y, b0.z, b0.w, b1.x, b1.y, b1.z, b1.w};
#pragma unroll
            for (int r = 0; r < 8; ++r)
#pragma unroll
                for (int cc = 0; cc < 8; ++cc)
                    acc[r][cc] = fmaf(av[r], bv[cc], acc[r][cc]);
        }
    }

#pragma unroll
    for (int r = 0; r < 8; ++r) {
        const size_t m = (size_t)(mt * 128 + ty * 8 + r);
        float4 o0 = {acc[r][0] + bia.x, acc[r][1] + bia.y,
                     acc[r][2] + bia.z, acc[r][3] + bia.w};
        float4 o1 = {acc[r][4] + bib.x, acc[r][5] + bib.y,
                     acc[r][6] + bib.z, acc[r][7] + bib.w};
        *reinterpret_cast<float4*>(&XG[m * G_SZ + n0])     = o0;
        *reinterpret_cast<float4*>(&XG[m * G_SZ + n0 + 4]) = o1;
    }
}

// ---------------------------------------------------------------------------
// Recurrence, register-h + readlane broadcast. 256 threads (4 waves, wave =
// gate). Lane l of wave g owns full gate row g*64+l: 64 W_hh floats pinned.
// h/c are REPLICATED per wave in lane registers (lane l = unit l). The h-dot
// fetches h[k] cross-lane via v_readlane -> SGPR operand of v_fma: ZERO LDS
// traffic for h (was 64 ds_read_b128/step = the R7/R10 throughput wall).
// Per step LDS: 1 xg b32 read + 1 gs write + 4 gs reads per wave + 1 barrier.
// ---------------------------------------------------------------------------
__global__ __launch_bounds__(256, 1) void lstm_rec(
    const float* __restrict__ XG,     // [TC,B,256]
    const float* __restrict__ W_hh,   // [256,64]
    float* __restrict__ h_state,      // [B,64]
    float* __restrict__ c_state,      // [B,64]
    int TC, int first)
{
    const int b = blockIdx.x;
    const int t = threadIdx.x;
    const int l = t & 63;             // lane = unit (cell phase)
    const int g = t >> 6;             // wave = gate: 0=i 1=f 2=g 3=o
    const int row = t;                // gate row g*64+l

    __shared__ __align__(16) float xgl[2][SUB][G_SZ];   // 64 KB
    __shared__ float gs[2][G_SZ];                       // double-buffered gates

    // full W_hh row -> 64 pinned register floats (R8-proven resident)
    const float* ur = W_hh + row * H_SZ;
    f32x8 w0, w1, w2, w3, w4, w5, w6, w7;
    LD8PIN(w0, ur)      LD8PIN(w1, ur +  8) LD8PIN(w2, ur + 16) LD8PIN(w3, ur + 24)
    LD8PIN(w4, ur + 32) LD8PIN(w5, ur + 40) LD8PIN(w6, ur + 48) LD8PIN(w7, ur + 56)

    // replicated state in lane registers (every wave: lane l = unit l)
    float h = first ? 0.0f : h_state[b * H_SZ + l];
    float c = first ? 0.0f : c_state[b * H_SZ + l];

    // stage sub-chunk 0: flat coalesced copy (thread t copies f4 #t+256i)
    {
        float* xf = &xgl[0][0][0];
#pragma unroll
        for (int i = 0; i < 8; ++i) {
            const int F = t + 256 * i;            // float4 index 0..2047
            const int r = F >> 6, cw = F & 63;    // step row, float4 col
            *reinterpret_cast<float4*>(xf + 4 * F) =
                *reinterpret_cast<const float4*>(
                    XG + ((size_t)r * B_SZ + b) * G_SZ + 4 * cw);
        }
    }
    __syncthreads();

    const bool isg = (g == 2);        // wave-uniform
    const int nsub = TC / SUB;
    int db = 0;

    for (int sub = 0; sub < nsub; ++sub) {
        const int cur = sub & 1;
        if (sub + 1 < nsub) {         // stage next sub-chunk (flat copy)
            float* xf = &xgl[cur ^ 1][0][0];
#pragma unroll
            for (int i = 0; i < 8; ++i) {
                const int F = t + 256 * i;
                const int r = (F >> 6) + (sub + 1) * SUB, cw = F & 63;
                *reinterpret_cast<float4*>(xf + 4 * F) =
                    *reinterpret_cast<const float4*>(
                        XG + ((size_t)r * B_SZ + b) * G_SZ + 4 * cw);
            }
        }

#pragma unroll 4
        for (int ts = 0; ts < SUB; ++ts) {
            // h-dot: 64 readlane + 64 FMA (VALU only), 4 chains
            const unsigned hu = __float_as_uint(h);
            float a0 = xgl[cur][ts][row];         // xg seed (banks 0..31, free)
            float a1 = 0.0f, a2 = 0.0f, a3 = 0.0f;
            RL8(w0,  0) RL8(w1,  8) RL8(w2, 16) RL8(w3, 24)
            RL8(w4, 32) RL8(w5, 40) RL8(w6, 48) RL8(w7, 56)
            const float acc = (a0 + a1) + (a2 + a3);

            // activation (wave-uniform gate; branchless select)
            const float arg = isg ? (-2.0f * acc) : (-acc);
            const float e = __expf(arg);
            const float r = __builtin_amdgcn_rcpf(1.0f + e);
            const float a = isg ? (1.0f - e) * r : r;

            gs[db][row] = a;                      // banks 0..31, conflict-free
            __syncthreads();                      // gates visible

            // replicated cell update: lane l handles unit l (4 free b32 reads)
            const float ig = gs[db][l];
            const float fg = gs[db][H_SZ + l];
            const float gg = gs[db][2 * H_SZ + l];
            const float og = gs[db][3 * H_SZ + l];
            c = fmaf(fg, c, ig * gg);
            h = og * fast_tanh(c);                // stays in registers
            db ^= 1;
        }
    }

    if (t < H_SZ) {                               // wave 0 writes final state
        h_state[b * H_SZ + t] = h;
        c_state[b * H_SZ + t] = c;
    }
}

// ---------------------------------------------------------------------------
// Reverse single cell (zero init state; W_hh_r drops out) + MLP head.
// ---------------------------------------------------------------------------
__global__ __launch_bounds__(256, 1) void lstm_tail(
    const float* __restrict__ x_last,  // [B,I]
    const float* __restrict__ W_ih_r,  // [256,128]
    const float* __restrict__ b_r,     // [256]
    const float* __restrict__ h_fwd,   // [B,64]
    const float* __restrict__ fc1_w,   // [64,128]
    const float* __restrict__ fc1_b,   // [64]
    const float* __restrict__ fc2_w,   // [32,64]
    const float* __restrict__ fc2_b,   // [32]
    const float* __restrict__ fc3_w,   // [10,32]
    const float* __restrict__ fc3_b,   // [10]
    float* __restrict__ out)           // [B,10]
{
    const int b = blockIdx.x;
    const int j = threadIdx.x;

    __shared__ float xs[I_SZ];
    __shared__ float gs[G_SZ];
    __shared__ float hc[2 * H_SZ];
    __shared__ float h1[64];
    __shared__ float h2[32];

    if (j < I_SZ) xs[j] = x_last[(size_t)b * I_SZ + j];
    if (j < H_SZ) hc[j] = h_fwd[b * H_SZ + j];
    __syncthreads();

    float a0 = b_r[j], a1 = 0.0f, a2 = 0.0f, a3 = 0.0f;
    const float* wrow = W_ih_r + j * I_SZ;
#pragma unroll
    for (int kk = 0; kk < I_SZ; kk += 4) {
        float4 wv = *reinterpret_cast<const float4*>(wrow + kk);
        a0 = fmaf(xs[kk + 0], wv.x, a0);
        a1 = fmaf(xs[kk + 1], wv.y, a1);
        a2 = fmaf(xs[kk + 2], wv.z, a2);
        a3 = fmaf(xs[kk + 3], wv.w, a3);
    }
    const float acc = (a0 + a1) + (a2 + a3);
    const int gate = j >> 6;
    gs[j] = (gate == 2) ? tanhf(acc) : 1.0f / (1.0f + expf(-acc));
    __syncthreads();

    if (j < H_SZ) {
        const float cc = gs[j] * gs[2 * H_SZ + j];     // i*g (c0 = 0)
        hc[H_SZ + j] = gs[3 * H_SZ + j] * tanhf(cc);
    }
    __syncthreads();

    if (j < 64) {
        float s0 = fc1_b[j], s1 = 0.0f, s2 = 0.0f, s3 = 0.0f;
        const float* w = fc1_w + j * 128;
#pragma unroll
        for (int kk = 0; kk < 128; kk += 4) {
            float4 wv = *reinterpret_cast<const float4*>(w + kk);
            s0 = fmaf(hc[kk + 0], wv.x, s0);
            s1 = fmaf(hc[kk + 1], wv.y, s1);
            s2 = fmaf(hc[kk + 2], wv.z, s2);
            s3 = fmaf(hc[kk + 3], wv.w, s3);
        }
        h1[j] = fmaxf((s0 + s1) + (s2 + s3), 0.0f);
    }
    __syncthreads();

    if (j < 32) {
        float s0 = fc2_b[j], s1 = 0.0f, s2 = 0.0f, s3 = 0.0f;
        const float* w = fc2_w + j * 64;
#pragma unroll
        for (int kk = 0; kk < 64; kk += 4) {
            float4 wv = *reinterpret_cast<const float4*>(w + kk);
            s0 = fmaf(h1[kk + 0], wv.x, s0);
            s1 = fmaf(h1[kk + 1], wv.y, s1);
            s2 = fmaf(h1[kk + 2], wv.z, s2);
            s3 = fmaf(h1[kk + 3], wv.w, s3);
        }
        h2[j] = fmaxf((s0 + s1) + (s2 + s3), 0.0f);
    }
    __syncthreads();

    if (j < 10) {
        float s = fc3_b[j];
#pragma unroll
        for (int kk = 0; kk < 32; ++kk) s = fmaf(h2[kk], fc3_w[j * 32 + kk], s);
        out[b * 10 + j] = s;
    }
}

extern "C" void kernel_launch(void* const* d_in, const int* in_sizes, int n_in,
                              void* d_out, int out_size, void* d_ws, size_t ws_size,
                              hipStream_t stream) {
    const float* x      = (const float*)d_in[0];
    const float* W_ih_f = (const float*)d_in[1];
    const float* W_hh_f = (const float*)d_in[2];
    const float* b_f    = (const float*)d_in[3];
    const float* W_ih_r = (const float*)d_in[4];
    // d_in[5] = W_hh_r : unused (zero initial state in reverse single step)
    const float* b_r    = (const float*)d_in[6];
    const float* fc1_w  = (const float*)d_in[7];
    const float* fc1_b  = (const float*)d_in[8];
    const float* fc2_w  = (const float*)d_in[9];
    const float* fc2_b  = (const float*)d_in[10];
    const float* fc3_w  = (const float*)d_in[11];
    const float* fc3_b  = (const float*)d_in[12];
    float* out = (float*)d_out;

    // time-chunk size: largest TC whose XG buffer (+state) fits in ws
    int TC = 1024;
    while (TC > 64 &&
           (size_t)TC * B_SZ * G_SZ * 4 + 2 * B_SZ * H_SZ * 4 > ws_size)
        TC >>= 1;

    float* XG      = (float*)d_ws;
    float* h_state = (float*)((char*)d_ws + (size_t)TC * B_SZ * G_SZ * 4);
    float* c_state = h_state + B_SZ * H_SZ;

    const int NCH = T_LEN / TC;
    for (int ch = 0; ch < NCH; ++ch) {
        const float* xch = x + (size_t)ch * TC * B_SZ * I_SZ;
        hipLaunchKernelGGL(xg_gemm, dim3(TC * B_SZ / 128, 2), dim3(256), 0,
                           stream, xch, W_ih_f, b_f, XG);
        hipLaunchKernelGGL(lstm_rec, dim3(B_SZ), dim3(256), 0, stream,
                           XG, W_hh_f, h_state, c_state, TC, ch == 0 ? 1 : 0);
    }

    const float* x_last = x + (size_t)(T_LEN - 1) * B_SZ * I_SZ;
    hipLaunchKernelGGL(lstm_tail, dim3(B_SZ), dim3(256), 0, stream,
                       x_last, W_ih_r, b_r, h_state,
                       fc1_w, fc1_b, fc2_w, fc2_b, fc3_w, fc3_b, out);
}

// Round 13
// 607.169 us; speedup vs baseline: 1.3308x; 1.0622x over previous
//
#include <hip/hip_runtime.h>
#include <math.h>

#define T_LEN 1024
#define B_SZ  256
#define I_SZ  128
#define H_SZ  64
#define G_SZ  256   // 4*H
#define SUB   32    // recurrence steps per LDS-staged XG sub-chunk

typedef float f32x8 __attribute__((ext_vector_type(8)));

__device__ __forceinline__ float fast_tanh(float x) {   // safe for any |x|
    float e = __expf(-2.0f * fabsf(x));
    float r = (1.0f - e) * __builtin_amdgcn_rcpf(1.0f + e);
    return copysignf(r, x);
}

#define LD8PIN(V, P)                                                        \
    {   float4 t0_ = *reinterpret_cast<const float4*>(P);                   \
        float4 t1_ = *reinterpret_cast<const float4*>((P) + 4);             \
        V = (f32x8){t0_.x, t0_.y, t0_.z, t0_.w, t1_.x, t1_.y, t1_.z, t1_.w};\
        asm volatile("" : "+v"(V)); }

// acc(4 chains) += h[K..K+7]*V[0..7], h via v_readlane (VALU pipe, no LDS).
// K must be a COMPILE-TIME literal: readlane lane-index must be wave-uniform
// (R12 lesson: divergent index = UB -> silent corruption).
#define RL8(V, K)                                                           \
    {   unsigned r0_ = __builtin_amdgcn_readlane(hu, (K) + 0);              \
        unsigned r1_ = __builtin_amdgcn_readlane(hu, (K) + 1);              \
        unsigned r2_ = __builtin_amdgcn_readlane(hu, (K) + 2);              \
        unsigned r3_ = __builtin_amdgcn_readlane(hu, (K) + 3);              \
        a0 = fmaf(__uint_as_float(r0_), V[0], a0);                          \
        a1 = fmaf(__uint_as_float(r1_), V[1], a1);                          \
        a2 = fmaf(__uint_as_float(r2_), V[2], a2);                          \
        a3 = fmaf(__uint_as_float(r3_), V[3], a3);                          \
        unsigned r4_ = __builtin_amdgcn_readlane(hu, (K) + 4);              \
        unsigned r5_ = __builtin_amdgcn_readlane(hu, (K) + 5);              \
        unsigned r6_ = __builtin_amdgcn_readlane(hu, (K) + 6);              \
        unsigned r7_ = __builtin_amdgcn_readlane(hu, (K) + 7);              \
        a0 = fmaf(__uint_as_float(r4_), V[4], a0);                          \
        a1 = fmaf(__uint_as_float(r5_), V[5], a1);                          \
        a2 = fmaf(__uint_as_float(r6_), V[6], a2);                          \
        a3 = fmaf(__uint_as_float(r7_), V[7], a3); }

// LDS column swizzle for the GEMM tiles
__device__ __forceinline__ int swz(int c) { return c + 4 * (c >> 5); }

// GEMM staging: global -> regs (issued early, latency hidden under compute)
#define GLOAD(K0)                                                           \
    { _Pragma("unroll") for (int i_ = 0; i_ < 4; ++i_) {                    \
        const int mr_ = srow + 32 * i_;                                     \
        pa[i_] = *reinterpret_cast<const float4*>(                          \
            &xch[(size_t)(mt * 128 + mr_) * I_SZ + (K0) + skk]);            \
        pb[i_] = *reinterpret_cast<const float4*>(                          \
            &W_ih[(size_t)(nt * 128 + mr_) * I_SZ + (K0) + skk]); } }

// GEMM staging: regs -> LDS (after compute; one barrier per stage)
#define SWRITE(BUF)                                                         \
    { _Pragma("unroll") for (int i_ = 0; i_ < 4; ++i_) {                    \
        const int mr_ = srow + 32 * i_; const int sm_ = swz(mr_);           \
        as[BUF][skk + 0][sm_] = pa[i_].x; as[BUF][skk + 1][sm_] = pa[i_].y; \
        as[BUF][skk + 2][sm_] = pa[i_].z; as[BUF][skk + 3][sm_] = pa[i_].w; \
        bs[BUF][skk + 0][sm_] = pb[i_].x; bs[BUF][skk + 1][sm_] = pb[i_].y; \
        bs[BUF][skk + 2][sm_] = pb[i_].z; bs[BUF][skk + 3][sm_] = pb[i_].w; } }

// ---------------------------------------------------------------------------
// XG GEMM, double-buffered: XG[m][n] = dot(x[m][:], W_ih[n][:]) + bias[n].
// 128x128 tile, 8x8 microtile, K staged in 4x32 with register prefetch:
// issue stage k+1 global loads BEFORE stage k compute (2048 FMA/thread hides
// ~500cyc HBM latency), write regs->LDS after, ONE barrier per stage.
// ---------------------------------------------------------------------------
__global__ __launch_bounds__(256, 2) void xg_gemm(
    const float* __restrict__ xch,    // [Mc,128] chunk of x
    const float* __restrict__ W_ih,   // [256,128]
    const float* __restrict__ bias,   // [256]
    float* __restrict__ XG)           // [Mc,256]
{
    const int tid = threadIdx.x;
    const int tx  = tid & 15;
    const int ty  = tid >> 4;
    const int mt  = blockIdx.x;
    const int nt  = blockIdx.y;

    __shared__ __align__(16) float as[2][32][140];   // 35.8 KB
    __shared__ __align__(16) float bs[2][32][140];   // 35.8 KB

    const int n0 = nt * 128 + tx * 8;
    float4 bia = *reinterpret_cast<const float4*>(&bias[n0]);
    float4 bib = *reinterpret_cast<const float4*>(&bias[n0 + 4]);

    float acc[8][8];
#pragma unroll
    for (int r = 0; r < 8; ++r)
#pragma unroll
        for (int cc = 0; cc < 8; ++cc) acc[r][cc] = 0.0f;

    const int srow = tid >> 3;            // 0..31
    const int skk  = (tid & 7) * 4;       // 0,4,..,28

    float4 pa[4], pb[4];
    GLOAD(0) SWRITE(0)
    __syncthreads();

#pragma unroll
    for (int ks = 0; ks < 4; ++ks) {
        if (ks < 3) GLOAD((ks + 1) * 32)  // prefetch next stage (in flight)

        const int buf = ks & 1;
#pragma unroll 8
        for (int kk = 0; kk < 32; ++kk) {
            const float4 a0 = *reinterpret_cast<const float4*>(&as[buf][kk][swz(ty * 8)]);
            const float4 a1 = *reinterpret_cast<const float4*>(&as[buf][kk][swz(ty * 8) + 4]);
            const float4 b0 = *reinterpret_cast<const float4*>(&bs[buf][kk][swz(tx * 8)]);
            const float4 b1 = *reinterpret_cast<const float4*>(&bs[buf][kk][swz(tx * 8) + 4]);
            const float av[8] = {a0.x, a0.y, a0.z, a0.w, a1.x, a1.y, a1.z, a1.w};
            const float bv[8] = {b0.x, b0.y, b0.z, b0.w, b1.x, b1.y, b1.z, b1.w};
#pragma unroll
            for (int r = 0; r < 8; ++r)
#pragma unroll
                for (int cc = 0; cc < 8; ++cc)
                    acc[r][cc] = fmaf(av[r], bv[cc], acc[r][cc]);
        }

        if (ks < 3) {
            SWRITE(buf ^ 1)               // prev readers of buf^1 done (bar ks-1)
            __syncthreads();              // one barrier per stage
        }
    }

#pragma unroll
    for (int r = 0; r < 8; ++r) {
        const size_t m = (size_t)(mt * 128 + ty * 8 + r);
        float4 o0 = {acc[r][0] + bia.x, acc[r][1] + bia.y,
                     acc[r][2] + bia.z, acc[r][3] + bia.w};
        float4 o1 = {acc[r][4] + bib.x, acc[r][5] + bib.y,
                     acc[r][6] + bib.z, acc[r][7] + bib.w};
        *reinterpret_cast<float4*>(&XG[m * G_SZ + n0])     = o0;
        *reinterpret_cast<float4*>(&XG[m * G_SZ + n0 + 4]) = o1;
    }
}

// ---------------------------------------------------------------------------
// Recurrence, register-h + readlane broadcast (R11, proven: 404us, 1.9e-6).
// 256 threads (4 waves, wave = gate). Lane l of wave g owns full gate row
// g*64+l: 64 W_hh floats pinned. h/c REPLICATED per wave in lane registers
// (lane l = unit l). h-dot fetches h[k] via v_readlane with LITERAL indices
// -> SGPR operand of v_fma: zero LDS traffic for h.
// ---------------------------------------------------------------------------
__global__ __launch_bounds__(256, 1) void lstm_rec(
    const float* __restrict__ XG,     // [TC,B,256]
    const float* __restrict__ W_hh,   // [256,64]
    float* __restrict__ h_state,      // [B,64]
    float* __restrict__ c_state,      // [B,64]
    int TC, int first)
{
    const int b = blockIdx.x;
    const int t = threadIdx.x;
    const int l = t & 63;             // lane = unit (cell phase)
    const int g = t >> 6;             // wave = gate: 0=i 1=f 2=g 3=o
    const int row = t;                // gate row g*64+l

    __shared__ __align__(16) float xgl[2][SUB][G_SZ];   // 64 KB
    __shared__ float gs[2][G_SZ];                       // double-buffered gates

    // full W_hh row -> 64 pinned register floats (R8-proven resident)
    const float* ur = W_hh + row * H_SZ;
    f32x8 w0, w1, w2, w3, w4, w5, w6, w7;
    LD8PIN(w0, ur)      LD8PIN(w1, ur +  8) LD8PIN(w2, ur + 16) LD8PIN(w3, ur + 24)
    LD8PIN(w4, ur + 32) LD8PIN(w5, ur + 40) LD8PIN(w6, ur + 48) LD8PIN(w7, ur + 56)

    // replicated state in lane registers (every wave: lane l = unit l)
    float h = first ? 0.0f : h_state[b * H_SZ + l];
    float c = first ? 0.0f : c_state[b * H_SZ + l];

    // stage sub-chunk 0: flat coalesced copy (thread t copies f4 #t+256i)
    {
        float* xf = &xgl[0][0][0];
#pragma unroll
        for (int i = 0; i < 8; ++i) {
            const int F = t + 256 * i;            // float4 index 0..2047
            const int r = F >> 6, cw = F & 63;    // step row, float4 col
            *reinterpret_cast<float4*>(xf + 4 * F) =
                *reinterpret_cast<const float4*>(
                    XG + ((size_t)r * B_SZ + b) * G_SZ + 4 * cw);
        }
    }
    __syncthreads();

    const bool isg = (g == 2);        // wave-uniform
    const int nsub = TC / SUB;
    int db = 0;

    for (int sub = 0; sub < nsub; ++sub) {
        const int cur = sub & 1;
        if (sub + 1 < nsub) {         // stage next sub-chunk (flat copy)
            float* xf = &xgl[cur ^ 1][0][0];
#pragma unroll
            for (int i = 0; i < 8; ++i) {
                const int F = t + 256 * i;
                const int r = (F >> 6) + (sub + 1) * SUB, cw = F & 63;
                *reinterpret_cast<float4*>(xf + 4 * F) =
                    *reinterpret_cast<const float4*>(
                        XG + ((size_t)r * B_SZ + b) * G_SZ + 4 * cw);
            }
        }

#pragma unroll 4
        for (int ts = 0; ts < SUB; ++ts) {
            // h-dot: 64 readlane + 64 FMA (VALU only), 4 chains
            const unsigned hu = __float_as_uint(h);
            float a0 = xgl[cur][ts][row];         // xg seed (banks 0..31, free)
            float a1 = 0.0f, a2 = 0.0f, a3 = 0.0f;
            RL8(w0,  0) RL8(w1,  8) RL8(w2, 16) RL8(w3, 24)
            RL8(w4, 32) RL8(w5, 40) RL8(w6, 48) RL8(w7, 56)
            const float acc = (a0 + a1) + (a2 + a3);

            // activation (wave-uniform gate; branchless select)
            const float arg = isg ? (-2.0f * acc) : (-acc);
            const float e = __expf(arg);
            const float r = __builtin_amdgcn_rcpf(1.0f + e);
            const float a = isg ? (1.0f - e) * r : r;

            gs[db][row] = a;                      // banks 0..31, conflict-free
            __syncthreads();                      // gates visible

            // replicated cell update: lane l handles unit l (4 free b32 reads)
            const float ig = gs[db][l];
            const float fg = gs[db][H_SZ + l];
            const float gg = gs[db][2 * H_SZ + l];
            const float og = gs[db][3 * H_SZ + l];
            c = fmaf(fg, c, ig * gg);
            h = og * fast_tanh(c);                // stays in registers
            db ^= 1;
        }
    }

    if (t < H_SZ) {                               // wave 0 writes final state
        h_state[b * H_SZ + t] = h;
        c_state[b * H_SZ + t] = c;
    }
}

// ---------------------------------------------------------------------------
// Reverse single cell (zero init state; W_hh_r drops out) + MLP head.
// ---------------------------------------------------------------------------
__global__ __launch_bounds__(256, 1) void lstm_tail(
    const float* __restrict__ x_last,  // [B,I]
    const float* __restrict__ W_ih_r,  // [256,128]
    const float* __restrict__ b_r,     // [256]
    const float* __restrict__ h_fwd,   // [B,64]
    const float* __restrict__ fc1_w,   // [64,128]
    const float* __restrict__ fc1_b,   // [64]
    const float* __restrict__ fc2_w,   // [32,64]
    const float* __restrict__ fc2_b,   // [32]
    const float* __restrict__ fc3_w,   // [10,32]
    const float* __restrict__ fc3_b,   // [10]
    float* __restrict__ out)           // [B,10]
{
    const int b = blockIdx.x;
    const int j = threadIdx.x;

    __shared__ float xs[I_SZ];
    __shared__ float gs[G_SZ];
    __shared__ float hc[2 * H_SZ];
    __shared__ float h1[64];
    __shared__ float h2[32];

    if (j < I_SZ) xs[j] = x_last[(size_t)b * I_SZ + j];
    if (j < H_SZ) hc[j] = h_fwd[b * H_SZ + j];
    __syncthreads();

    float a0 = b_r[j], a1 = 0.0f, a2 = 0.0f, a3 = 0.0f;
    const float* wrow = W_ih_r + j * I_SZ;
#pragma unroll
    for (int kk = 0; kk < I_SZ; kk += 4) {
        float4 wv = *reinterpret_cast<const float4*>(wrow + kk);
        a0 = fmaf(xs[kk + 0], wv.x, a0);
        a1 = fmaf(xs[kk + 1], wv.y, a1);
        a2 = fmaf(xs[kk + 2], wv.z, a2);
        a3 = fmaf(xs[kk + 3], wv.w, a3);
    }
    const float acc = (a0 + a1) + (a2 + a3);
    const int gate = j >> 6;
    gs[j] = (gate == 2) ? tanhf(acc) : 1.0f / (1.0f + expf(-acc));
    __syncthreads();

    if (j < H_SZ) {
        const float cc = gs[j] * gs[2 * H_SZ + j];     // i*g (c0 = 0)
        hc[H_SZ + j] = gs[3 * H_SZ + j] * tanhf(cc);
    }
    __syncthreads();

    if (j < 64) {
        float s0 = fc1_b[j], s1 = 0.0f, s2 = 0.0f, s3 = 0.0f;
        const float* w = fc1_w + j * 128;
#pragma unroll
        for (int kk = 0; kk < 128; kk += 4) {
            float4 wv = *reinterpret_cast<const float4*>(w + kk);
            s0 = fmaf(hc[kk + 0], wv.x, s0);
            s1 = fmaf(hc[kk + 1], wv.y, s1);
            s2 = fmaf(hc[kk + 2], wv.z, s2);
            s3 = fmaf(hc[kk + 3], wv.w, s3);
        }
        h1[j] = fmaxf((s0 + s1) + (s2 + s3), 0.0f);
    }
    __syncthreads();

    if (j < 32) {
        float s0 = fc2_b[j], s1 = 0.0f, s2 = 0.0f, s3 = 0.0f;
        const float* w = fc2_w + j * 64;
#pragma unroll
        for (int kk = 0; kk < 64; kk += 4) {
            float4 wv = *reinterpret_cast<const float4*>(w + kk);
            s0 = fmaf(h1[kk + 0], wv.x, s0);
            s1 = fmaf(h1[kk + 1], wv.y, s1);
            s2 = fmaf(h1[kk + 2], wv.z, s2);
            s3 = fmaf(h1[kk + 3], wv.w, s3);
        }
        h2[j] = fmaxf((s0 + s1) + (s2 + s3), 0.0f);
    }
    __syncthreads();

    if (j < 10) {
        float s = fc3_b[j];
#pragma unroll
        for (int kk = 0; kk < 32; ++kk) s = fmaf(h2[kk], fc3_w[j * 32 + kk], s);
        out[b * 10 + j] = s;
    }
}

extern "C" void kernel_launch(void* const* d_in, const int* in_sizes, int n_in,
                              void* d_out, int out_size, void* d_ws, size_t ws_size,
                              hipStream_t stream) {
    const float* x      = (const float*)d_in[0];
    const float* W_ih_f = (const float*)d_in[1];
    const float* W_hh_f = (const float*)d_in[2];
    const float* b_f    = (const float*)d_in[3];
    const float* W_ih_r = (const float*)d_in[4];
    // d_in[5] = W_hh_r : unused (zero initial state in reverse single step)
    const float* b_r    = (const float*)d_in[6];
    const float* fc1_w  = (const float*)d_in[7];
    const float* fc1_b  = (const float*)d_in[8];
    const float* fc2_w  = (const float*)d_in[9];
    const float* fc2_b  = (const float*)d_in[10];
    const float* fc3_w  = (const float*)d_in[11];
    const float* fc3_b  = (const float*)d_in[12];
    float* out = (float*)d_out;

    // time-chunk size: largest TC whose XG buffer (+state) fits in ws
    int TC = 1024;
    while (TC > 64 &&
           (size_t)TC * B_SZ * G_SZ * 4 + 2 * B_SZ * H_SZ * 4 > ws_size)
        TC >>= 1;

    float* XG      = (float*)d_ws;
    float* h_state = (float*)((char*)d_ws + (size_t)TC * B_SZ * G_SZ * 4);
    float* c_state = h_state + B_SZ * H_SZ;

    const int NCH = T_LEN / TC;
    for (int ch = 0; ch < NCH; ++ch) {
        const float* xch = x + (size_t)ch * TC * B_SZ * I_SZ;
        hipLaunchKernelGGL(xg_gemm, dim3(TC * B_SZ / 128, 2), dim3(256), 0,
                           stream, xch, W_ih_f, b_f, XG);
        hipLaunchKernelGGL(lstm_rec, dim3(B_SZ), dim3(256), 0, stream,
                           XG, W_hh_f, h_state, c_state, TC, ch == 0 ? 1 : 0);
    }

    const float* x_last = x + (size_t)(T_LEN - 1) * B_SZ * I_SZ;
    hipLaunchKernelGGL(lstm_tail, dim3(B_SZ), dim3(256), 0, stream,
                       x_last, W_ih_r, b_r, h_state,
                       fc1_w, fc1_b, fc2_w, fc2_b, fc3_w, fc3_b, out);
}